// Round 3
// baseline (510.086 us; speedup 1.0000x reference)
//
#include <hip/hip_runtime.h>
#include <hip/hip_bf16.h>

#define E_ 4
#define M_ 4096
#define D_ 1024
#define NIT 4
#define THRESH_ 0.01f

typedef __attribute__((ext_vector_type(8))) short bf16x8;
typedef __attribute__((ext_vector_type(4))) float f32x4;

__device__ inline unsigned short f2bf(float x) {
    unsigned u = __float_as_uint(x);
    unsigned r = (u + 0x7FFFu + ((u >> 16) & 1u)) >> 16;  // RNE
    return (unsigned short)r;
}

__device__ inline float Kf(float s) {            // K = exp(10*(sim-1))
    return __expf(fmaf(10.f, s, -10.f));
}

__device__ inline void unpack8(const int4& raw, float* s) {
    const unsigned* pu = reinterpret_cast<const unsigned*>(&raw);
#pragma unroll
    for (int j = 0; j < 4; ++j) {
        s[2*j]   = __uint_as_float(pu[j] << 16);
        s[2*j+1] = __uint_as_float(pu[j] & 0xFFFF0000u);
    }
}

// ---------------- normalize rows + convert to bf16 ----------------
__global__ __launch_bounds__(256)
void normalize_bf16(const float* __restrict__ g, const float* __restrict__ f,
                    __hip_bfloat16* __restrict__ Sb, __hip_bfloat16* __restrict__ Tb)
{
    const int w = threadIdx.x >> 6, l = threadIdx.x & 63;
    const size_t row = (size_t)blockIdx.x * 4 + w;       // 0..E*M-1
    const float* src = (blockIdx.y == 0 ? g : f) + row * (size_t)D_;
    __hip_bfloat16* dst = (blockIdx.y == 0 ? Sb : Tb) + row * (size_t)D_;
    float4 v[4];
    float ss = 0.f;
#pragma unroll
    for (int i = 0; i < 4; ++i) {
        v[i] = *(const float4*)(src + (i*64 + l) * 4);
        ss += v[i].x*v[i].x + v[i].y*v[i].y + v[i].z*v[i].z + v[i].w*v[i].w;
    }
#pragma unroll
    for (int off = 32; off; off >>= 1) ss += __shfl_xor(ss, off);
    const float inv = 1.f / fmaxf(sqrtf(ss), 1e-12f);
#pragma unroll
    for (int i = 0; i < 4; ++i) {
        ushort4 o;
        o.x = f2bf(v[i].x * inv); o.y = f2bf(v[i].y * inv);
        o.z = f2bf(v[i].z * inv); o.w = f2bf(v[i].w * inv);
        *(ushort4*)((unsigned short*)dst + (i*64 + l) * 4) = o;
    }
}

// ---- bf16 NT-GEMM: Kmat = exp(10*(S@T^T - 1)) stored bf16; epilogue Kc0 = K @ 1 ----
__global__ __launch_bounds__(256)
void gemm_bt(const __hip_bfloat16* __restrict__ Sb, const __hip_bfloat16* __restrict__ Tb,
             __hip_bfloat16* __restrict__ Kmat, float* __restrict__ Kc0)
{
    const int e = blockIdx.z;
    const int brow = blockIdx.y, bcol = blockIdx.x;
    const int t = threadIdx.x, w = t >> 6, l = t & 63;
    const int wr = w >> 1, wc = w & 1;

    __shared__ __hip_bfloat16 Asl[128*32];
    __shared__ __hip_bfloat16 Bsl[128*32];

    const __hip_bfloat16* Ag = Sb + ((size_t)e*M_ + (size_t)brow*128) * D_;
    const __hip_bfloat16* Bg = Tb + ((size_t)e*M_ + (size_t)bcol*128) * D_;

    f32x4 acc[4][4] = {};

    for (int k0 = 0; k0 < D_; k0 += 32) {
#pragma unroll
        for (int i = 0; i < 2; ++i) {
            const int ci = i*256 + t;                 // 16B chunk id 0..511
            const int row = ci >> 2, c16 = ci & 3;
            const size_t goff = (size_t)row * D_ + k0 + c16*8;
            __builtin_amdgcn_global_load_lds(
                (const __attribute__((address_space(1))) void*)(Ag + goff),
                (__attribute__((address_space(3))) void*)(Asl + ci*8), 16, 0, 0);
            __builtin_amdgcn_global_load_lds(
                (const __attribute__((address_space(1))) void*)(Bg + goff),
                (__attribute__((address_space(3))) void*)(Bsl + ci*8), 16, 0, 0);
        }
        __syncthreads();
        bf16x8 af[4], bfr[4];
#pragma unroll
        for (int m = 0; m < 4; ++m)
            af[m] = *(const bf16x8*)(Asl + (wr*64 + m*16 + (l & 15)) * 32 + (l >> 4) * 8);
#pragma unroll
        for (int n = 0; n < 4; ++n)
            bfr[n] = *(const bf16x8*)(Bsl + (wc*64 + n*16 + (l & 15)) * 32 + (l >> 4) * 8);
#pragma unroll
        for (int m = 0; m < 4; ++m)
#pragma unroll
            for (int n = 0; n < 4; ++n)
                acc[m][n] = __builtin_amdgcn_mfma_f32_16x16x32_bf16(af[m], bfr[n], acc[m][n], 0, 0, 0);
        __syncthreads();
    }

    // C/D layout: col = lane&15, row = (lane>>4)*4 + reg
    unsigned short* Cg = (unsigned short*)(Kmat + (size_t)e*M_*M_);
    float* kc = Kc0 + e*M_;
    const size_t crow0 = (size_t)brow*128 + wr*64;
    const int ccol0 = bcol*128 + wc*64;
#pragma unroll
    for (int m = 0; m < 4; ++m)
#pragma unroll
        for (int j = 0; j < 4; ++j) {
            const size_t r = crow0 + m*16 + (l >> 4)*4 + j;
            float rs = 0.f;
#pragma unroll
            for (int n = 0; n < 4; ++n) {
                const float k = Kf(acc[m][n][j]);
                Cg[r * M_ + ccol0 + n*16 + (l & 15)] = f2bf(k);
                rs += k;
            }
            rs += __shfl_xor(rs, 1);
            rs += __shfl_xor(rs, 2);
            rs += __shfl_xor(rs, 4);
            rs += __shfl_xor(rs, 8);
            if ((l & 15) == 0) atomicAdd(&kc[r], rs);
        }
}

// ---------------- r update for it=0 from GEMM-fused Kc0 ----------------
__global__ __launch_bounds__(256)
void r_update0(const float* __restrict__ Kc0, float* __restrict__ r_cur,
               float* __restrict__ err)
{
    const int e = blockIdx.y;
    const int i = blockIdx.x * 256 + threadIdx.x;
    const float newr = (1.0f / M_) / Kc0[e*M_ + i];
    const float oldr = r_cur[e*M_ + i];              // = 1.0 from init
    r_cur[e*M_ + i] = newr;
    float d = fabsf(newr - oldr);
#pragma unroll
    for (int off = 32; off; off >>= 1) d += __shfl_down(d, off);
    __shared__ float bl[4];
    if ((threadIdx.x & 63) == 0) bl[threadIdx.x >> 6] = d;
    __syncthreads();
    if (threadIdx.x == 0) atomicAdd(&err[0*E_ + e], bl[0]+bl[1]+bl[2]+bl[3]);
}

// ------- it>=1: Kc[m] = sum_n K[m,n]*c[n] (pure fma); fused r update + err -------
__global__ __launch_bounds__(256)
void kc_rowmv(const __hip_bfloat16* __restrict__ Kmat, const float* __restrict__ c_cur,
              float* __restrict__ r_cur, float* __restrict__ err,
              const int* __restrict__ run, int it)
{
    const int e = blockIdx.y;
    if (!run[it*E_ + e]) return;
    const int w = threadIdx.x >> 6, l = threadIdx.x & 63;
    const int row = blockIdx.x * 4 + w;
    const unsigned short* rp = (const unsigned short*)Kmat + ((size_t)e*M_ + row) * M_;
    const float* cp = c_cur + e*M_;
    float p = 0.f;
#pragma unroll
    for (int i = 0; i < 8; ++i) {
        const int col = (i*64 + l) * 8;
        int4 raw = *(const int4*)(rp + col);
        float4 ca = *(const float4*)(cp + col);
        float4 cb = *(const float4*)(cp + col + 4);
        float k[8]; unpack8(raw, k);
        p += k[0]*ca.x + k[1]*ca.y + k[2]*ca.z + k[3]*ca.w
           + k[4]*cb.x + k[5]*cb.y + k[6]*cb.z + k[7]*cb.w;
    }
#pragma unroll
    for (int off = 32; off; off >>= 1) p += __shfl_down(p, off);
    __shared__ float bl[4];
    if (l == 0) {
        const float newr = (1.0f / M_) / p;
        const float oldr = r_cur[e*M_ + row];
        r_cur[e*M_ + row] = newr;
        bl[w] = fabsf(newr - oldr);
    }
    __syncthreads();
    if (threadIdx.x == 0) atomicAdd(&err[it*E_ + e], bl[0]+bl[1]+bl[2]+bl[3]);
}

// ------- partial[mc][n] = sum_{m in 64-chunk} K[m,n]*r[m] (pure fma) -------
__global__ __launch_bounds__(256)
void kt_colmv(const __hip_bfloat16* __restrict__ Kmat, const float* __restrict__ r_cur,
              float* __restrict__ part, const int* __restrict__ run, int it)
{
    const int e = blockIdx.z;
    if (!run[it*E_ + e]) return;
    const int mc = blockIdx.y;                           // 0..63
    const int n0 = blockIdx.x * 2048 + threadIdx.x * 8;
    __shared__ float rsh[64];
    if (threadIdx.x < 64) rsh[threadIdx.x] = r_cur[e*M_ + mc*64 + threadIdx.x];
    __syncthreads();
    const unsigned short* base = (const unsigned short*)Kmat + ((size_t)e*M_ + (size_t)mc*64) * M_ + n0;
    float acc[8] = {0.f,0.f,0.f,0.f,0.f,0.f,0.f,0.f};
#pragma unroll 4
    for (int m = 0; m < 64; ++m) {
        const float rm = rsh[m];
        int4 raw = *(const int4*)(base + (size_t)m * M_);
        float k[8]; unpack8(raw, k);
#pragma unroll
        for (int j = 0; j < 8; ++j) acc[j] = fmaf(rm, k[j], acc[j]);
    }
    const size_t po = (size_t)(e*64 + mc) * M_ + n0;
    float4 o0 = {acc[0], acc[1], acc[2], acc[3]};
    float4 o1 = {acc[4], acc[5], acc[6], acc[7]};
    *(float4*)(part + po) = o0;
    *(float4*)(part + po + 4) = o1;
}

// ---- c = v/colsum; fused convergence-flag update ----
__global__ __launch_bounds__(256)
void c_update(const float* __restrict__ part, float* __restrict__ c_cur,
              const float* __restrict__ err, int* __restrict__ run, int it)
{
    const int e = blockIdx.y;
    const int active = run[it*E_ + e];
    if (blockIdx.x == 0 && threadIdx.x == 0)
        run[(it+1)*E_ + e] = active && (err[it*E_ + e] * (1.0f / M_) >= THRESH_);
    if (!active) return;
    const int n = blockIdx.x * 256 + threadIdx.x;
    float s = 0.f;
#pragma unroll
    for (int mc = 0; mc < 64; ++mc) s += part[(size_t)(e*64 + mc) * M_ + n];
    c_cur[e*M_ + n] = (1.0f / M_) / s;
}

// ---- final loss: loss_e = sum r[m] c[n] K[m,n] sim[m,n], sim = 1 + 0.1*ln(K) ----
__global__ __launch_bounds__(256)
void loss_kernel(const __hip_bfloat16* __restrict__ Kmat, const float* __restrict__ r_cur,
                 const float* __restrict__ c_cur, float* __restrict__ loss_acc)
{
    const int e = blockIdx.z;
    const int mc = blockIdx.y;                           // 0..63
    const int n0 = blockIdx.x * 2048 + threadIdx.x * 8;
    __shared__ float rsh[64];
    if (threadIdx.x < 64) rsh[threadIdx.x] = r_cur[e*M_ + mc*64 + threadIdx.x];
    __syncthreads();
    float c8[8];
    {
        float4 ca = *(const float4*)(c_cur + e*M_ + n0);
        float4 cb = *(const float4*)(c_cur + e*M_ + n0 + 4);
        c8[0]=ca.x; c8[1]=ca.y; c8[2]=ca.z; c8[3]=ca.w;
        c8[4]=cb.x; c8[5]=cb.y; c8[6]=cb.z; c8[7]=cb.w;
    }
    const unsigned short* base = (const unsigned short*)Kmat + ((size_t)e*M_ + (size_t)mc*64) * M_ + n0;
    float p = 0.f;
#pragma unroll 2
    for (int m = 0; m < 64; ++m) {
        const float rm = rsh[m];
        int4 raw = *(const int4*)(base + (size_t)m * M_);
        float k[8]; unpack8(raw, k);
        float q = 0.f;
#pragma unroll
        for (int j = 0; j < 8; ++j) {
            const float sim = fmaf(0.0693147182f, __log2f(k[j]), 1.0f);  // 1 + 0.1*ln K
            q = fmaf(c8[j] * k[j], sim, q);
        }
        p = fmaf(rm, q, p);
    }
#pragma unroll
    for (int off = 32; off; off >>= 1) p += __shfl_down(p, off);
    __shared__ float bl[4];
    if ((threadIdx.x & 63) == 0) bl[threadIdx.x >> 6] = p;
    __syncthreads();
    if (threadIdx.x == 0) atomicAdd(&loss_acc[e], bl[0]+bl[1]+bl[2]+bl[3]);
}

// ---------------- init + final weighting ----------------
__global__ void init_rc(float* __restrict__ r_cur, int* __restrict__ run)
{
    const int i = blockIdx.x * 256 + threadIdx.x;
    if (i < E_*M_) r_cur[i] = 1.f;
    if (i < E_) run[i] = 1;
}

__global__ void finalize(const float* __restrict__ loss_acc, const float* __restrict__ prev,
                         float* __restrict__ out)
{
    if (threadIdx.x == 0 && blockIdx.x == 0) {
        float l[E_], wgt[E_], sw = 0.f, tot = 0.f;
        for (int e = 0; e < E_; ++e) {
            l[e] = loss_acc[e];
            wgt[e] = expf(l[e] / (prev[e] + 1e-8f));
            sw += wgt[e];
        }
        for (int e = 0; e < E_; ++e) tot += (wgt[e] / sw * (float)E_) * l[e];
        out[0] = tot;
    }
}

extern "C" void kernel_launch(void* const* d_in, const int* in_sizes, int n_in,
                              void* d_out, int out_size, void* d_ws, size_t ws_size,
                              hipStream_t stream)
{
    (void)in_sizes; (void)n_in; (void)out_size; (void)ws_size;
    const float* gts   = (const float*)d_in[0];
    const float* feats = (const float*)d_in[1];
    const float* prev  = (const float*)d_in[2];
    float* out = (float*)d_out;
    char* ws = (char*)d_ws;

    __hip_bfloat16* Kmat = (__hip_bfloat16*)ws;                      // 134,217,728 B
    __hip_bfloat16* Sb   = (__hip_bfloat16*)(ws + 134217728);        //  33,554,432 B
    __hip_bfloat16* Tb   = (__hip_bfloat16*)(ws + 167772160);        //  33,554,432 B
    float* part     = (float*)(ws + 201326592);                      //   4,194,304 B (64 chunks)
    float* Kc0      = (float*)(ws + 205520896);                      //      65,536 B
    float* r_cur    = (float*)(ws + 205586432);                      //      65,536 B
    float* c_cur    = (float*)(ws + 205651968);                      //      65,536 B
    float* err      = (float*)(ws + 205717504);                      //          64 B
    int*   run      = (int*)  (ws + 205717568);                      //          80 B
    float* loss_acc = (float*)(ws + 205717648);                      //          16 B

    hipMemsetAsync(err, 0, 160, stream);              // err + run + loss_acc
    hipMemsetAsync(Kc0, 0, E_*M_*sizeof(float), stream);
    init_rc<<<dim3(64), 256, 0, stream>>>(r_cur, run);
    normalize_bf16<<<dim3(E_*M_/4, 2), 256, 0, stream>>>(gts, feats, Sb, Tb);
    gemm_bt<<<dim3(32, 32, E_), 256, 0, stream>>>(Sb, Tb, Kmat, Kc0);

    // it = 0 (row matvec fused into GEMM epilogue)
    r_update0<<<dim3(M_/256, E_), 256, 0, stream>>>(Kc0, r_cur, err);
    kt_colmv<<<dim3(2, 64, E_), 256, 0, stream>>>(Kmat, r_cur, part, run, 0);
    c_update<<<dim3(M_/256, E_), 256, 0, stream>>>(part, c_cur, err, run, 0);

    for (int it = 1; it < NIT; ++it) {
        kc_rowmv<<<dim3(M_/4, E_), 256, 0, stream>>>(Kmat, c_cur, r_cur, err, run, it);
        kt_colmv<<<dim3(2, 64, E_), 256, 0, stream>>>(Kmat, r_cur, part, run, it);
        c_update<<<dim3(M_/256, E_), 256, 0, stream>>>(part, c_cur, err, run, it);
    }
    loss_kernel<<<dim3(2, 64, E_), 256, 0, stream>>>(Kmat, r_cur, c_cur, loss_acc);
    finalize<<<1, 64, 0, stream>>>(loss_acc, prev, out);
}

// Round 4
// 482.689 us; speedup vs baseline: 1.0568x; 1.0568x over previous
//
#include <hip/hip_runtime.h>
#include <hip/hip_bf16.h>

#define E_ 4
#define M_ 4096
#define D_ 1024
#define NIT 3
#define THRESH_ 0.01f
#define RCHUNK 16
#define NCHUNK (M_/RCHUNK)   // 256

typedef __attribute__((ext_vector_type(8))) short bf16x8;
typedef __attribute__((ext_vector_type(4))) float f32x4;

__device__ inline unsigned short f2bf(float x) {
    unsigned u = __float_as_uint(x);
    unsigned r = (u + 0x7FFFu + ((u >> 16) & 1u)) >> 16;  // RNE
    return (unsigned short)r;
}

__device__ inline float Kf(float s) {            // K = exp(10*(sim-1))
    return __expf(fmaf(10.f, s, -10.f));
}

// ---- custom fp8 for K: e4m3 bits of (K*2^13); decode returns UNSCALED K ----
// byte = clamp(((bits(K*8192)+RNE)>>20) - 960, 0, 255); K = as_float((byte+856)<<20)
__device__ inline unsigned char kenc(float k) {
    unsigned u = __float_as_uint(k * 8192.0f);
    u += 0x7FFFFu + ((u >> 20) & 1u);            // RNE to 3 mantissa bits
    int t = (int)(u >> 20) - 960;
    t = t < 0 ? 0 : (t > 255 ? 255 : t);
    return (unsigned char)t;
}

__device__ inline void kdec16(const int4& raw, float* k) {
    const unsigned* w = reinterpret_cast<const unsigned*>(&raw);
#pragma unroll
    for (int q = 0; q < 4; ++q) {
        const unsigned x = w[q];
        k[4*q+0] = __uint_as_float(((x & 0xFFu)         + 856u) << 20);
        k[4*q+1] = __uint_as_float((((x >> 8) & 0xFFu)  + 856u) << 20);
        k[4*q+2] = __uint_as_float((((x >> 16) & 0xFFu) + 856u) << 20);
        k[4*q+3] = __uint_as_float(( (x >> 24)          + 856u) << 20);
    }
}

// ---------------- normalize rows + convert to bf16 ----------------
__global__ __launch_bounds__(256)
void normalize_bf16(const float* __restrict__ g, const float* __restrict__ f,
                    __hip_bfloat16* __restrict__ Sb, __hip_bfloat16* __restrict__ Tb)
{
    const int w = threadIdx.x >> 6, l = threadIdx.x & 63;
    const size_t row = (size_t)blockIdx.x * 4 + w;       // 0..E*M-1
    const float* src = (blockIdx.y == 0 ? g : f) + row * (size_t)D_;
    __hip_bfloat16* dst = (blockIdx.y == 0 ? Sb : Tb) + row * (size_t)D_;
    float4 v[4];
    float ss = 0.f;
#pragma unroll
    for (int i = 0; i < 4; ++i) {
        v[i] = *(const float4*)(src + (i*64 + l) * 4);
        ss += v[i].x*v[i].x + v[i].y*v[i].y + v[i].z*v[i].z + v[i].w*v[i].w;
    }
#pragma unroll
    for (int off = 32; off; off >>= 1) ss += __shfl_xor(ss, off);
    const float inv = 1.f / fmaxf(sqrtf(ss), 1e-12f);
#pragma unroll
    for (int i = 0; i < 4; ++i) {
        ushort4 o;
        o.x = f2bf(v[i].x * inv); o.y = f2bf(v[i].y * inv);
        o.z = f2bf(v[i].z * inv); o.w = f2bf(v[i].w * inv);
        *(ushort4*)((unsigned short*)dst + (i*64 + l) * 4) = o;
    }
}

// ---- bf16 NT-GEMM: Kmat(fp8) = exp(10*(S@T^T - 1)); epilogue Kc0 = K @ 1 (f32) ----
__global__ __launch_bounds__(256)
void gemm_bt(const __hip_bfloat16* __restrict__ Sb, const __hip_bfloat16* __restrict__ Tb,
             unsigned char* __restrict__ Kmat, float* __restrict__ Kc0)
{
    const int e = blockIdx.z;
    const int brow = blockIdx.y, bcol = blockIdx.x;
    const int t = threadIdx.x, w = t >> 6, l = t & 63;
    const int wr = w >> 1, wc = w & 1;

    __shared__ __hip_bfloat16 Asl[128*32];
    __shared__ __hip_bfloat16 Bsl[128*32];

    const __hip_bfloat16* Ag = Sb + ((size_t)e*M_ + (size_t)brow*128) * D_;
    const __hip_bfloat16* Bg = Tb + ((size_t)e*M_ + (size_t)bcol*128) * D_;

    f32x4 acc[4][4] = {};

    for (int k0 = 0; k0 < D_; k0 += 32) {
#pragma unroll
        for (int i = 0; i < 2; ++i) {
            const int ci = i*256 + t;                 // 16B chunk id 0..511
            const int row = ci >> 2, c16 = ci & 3;
            const size_t goff = (size_t)row * D_ + k0 + c16*8;
            __builtin_amdgcn_global_load_lds(
                (const __attribute__((address_space(1))) void*)(Ag + goff),
                (__attribute__((address_space(3))) void*)(Asl + ci*8), 16, 0, 0);
            __builtin_amdgcn_global_load_lds(
                (const __attribute__((address_space(1))) void*)(Bg + goff),
                (__attribute__((address_space(3))) void*)(Bsl + ci*8), 16, 0, 0);
        }
        __syncthreads();
        bf16x8 af[4], bfr[4];
#pragma unroll
        for (int m = 0; m < 4; ++m)
            af[m] = *(const bf16x8*)(Asl + (wr*64 + m*16 + (l & 15)) * 32 + (l >> 4) * 8);
#pragma unroll
        for (int n = 0; n < 4; ++n)
            bfr[n] = *(const bf16x8*)(Bsl + (wc*64 + n*16 + (l & 15)) * 32 + (l >> 4) * 8);
#pragma unroll
        for (int m = 0; m < 4; ++m)
#pragma unroll
            for (int n = 0; n < 4; ++n)
                acc[m][n] = __builtin_amdgcn_mfma_f32_16x16x32_bf16(af[m], bfr[n], acc[m][n], 0, 0, 0);
        __syncthreads();
    }

    // C/D layout: col = lane&15, row = (lane>>4)*4 + reg
    unsigned char* Cg = Kmat + (size_t)e*M_*M_;
    float* kc = Kc0 + e*M_;
    const size_t crow0 = (size_t)brow*128 + wr*64;
    const int ccol0 = bcol*128 + wc*64;
#pragma unroll
    for (int m = 0; m < 4; ++m)
#pragma unroll
        for (int j = 0; j < 4; ++j) {
            const size_t r = crow0 + m*16 + (l >> 4)*4 + j;
            float rs = 0.f;
#pragma unroll
            for (int n = 0; n < 4; ++n) {
                const float k = Kf(acc[m][n][j]);
                Cg[r * M_ + ccol0 + n*16 + (l & 15)] = kenc(k);
                rs += k;
            }
            rs += __shfl_xor(rs, 1);
            rs += __shfl_xor(rs, 2);
            rs += __shfl_xor(rs, 4);
            rs += __shfl_xor(rs, 8);
            if ((l & 15) == 0) atomicAdd(&kc[r], rs);
        }
}

// ---- colsum pass: part[ch][n] = sum_{m in chunk} K[m,n]*r[m]
//      first=1: r = r1 = u/Kc0 computed inline, stored; err0 accumulated ----
__global__ __launch_bounds__(256)
void kt_colmv(const unsigned char* __restrict__ Kmat, const float* __restrict__ Kc0,
              float* __restrict__ r_cur, float* __restrict__ part,
              float* __restrict__ err, const int* __restrict__ run,
              int it, int first)
{
    const int e = blockIdx.y, ch = blockIdx.x, tid = threadIdx.x;
    if (!first && !run[it*E_ + e]) return;
    __shared__ float rsh[RCHUNK];
    if (first) {
        if (tid < RCHUNK) {
            const float r1 = 2.44140625e-4f / Kc0[e*M_ + ch*RCHUNK + tid];
            rsh[tid] = r1;
            r_cur[e*M_ + ch*RCHUNK + tid] = r1;
        }
        __syncthreads();
        if (tid == 0) {
            float s = 0.f;
#pragma unroll
            for (int i = 0; i < RCHUNK; ++i) s += fabsf(rsh[i] - 1.0f);
            atomicAdd(&err[e], s);                   // err[0*E_+e]
        }
    } else {
        if (tid < RCHUNK) rsh[tid] = r_cur[e*M_ + ch*RCHUNK + tid];
        __syncthreads();
    }
    const unsigned char* base = Kmat + ((size_t)e*M_ + (size_t)ch*RCHUNK) * M_ + tid*16;
    float acc[16];
#pragma unroll
    for (int j = 0; j < 16; ++j) acc[j] = 0.f;
#pragma unroll 4
    for (int m = 0; m < RCHUNK; ++m) {
        const float rm = rsh[m];
        int4 raw = *(const int4*)(base + (size_t)m * M_);
        float k[16]; kdec16(raw, k);
#pragma unroll
        for (int j = 0; j < 16; ++j) acc[j] = fmaf(rm, k[j], acc[j]);
    }
    float* pp = part + ((size_t)e*NCHUNK + ch) * M_ + tid*16;
#pragma unroll
    for (int q = 0; q < 4; ++q) {
        float4 o = {acc[4*q], acc[4*q+1], acc[4*q+2], acc[4*q+3]};
        *(float4*)(pp + 4*q) = o;
    }
}

// ---- c = v/colsum; fused convergence-flag update ----
__global__ __launch_bounds__(256)
void c_update(const float* __restrict__ part, float* __restrict__ c_cur,
              const float* __restrict__ err, int* __restrict__ run, int it)
{
    const int e = blockIdx.y;
    const int active = (it == 0) ? 1 : run[it*E_ + e];
    if (blockIdx.x == 0 && threadIdx.x == 0)
        run[(it+1)*E_ + e] = active && (err[it*E_ + e] * (1.0f / M_) >= THRESH_);
    if (!active) return;
    const int n = blockIdx.x * 256 + threadIdx.x;
    float s = 0.f;
#pragma unroll 8
    for (int ch = 0; ch < NCHUNK; ++ch) s += part[((size_t)e*NCHUNK + ch) * M_ + n];
    c_cur[e*M_ + n] = 2.44140625e-4f / s;
}

// ---- row pass (it>=1): Kc[m] = sum_n K[m,n]*c[n]; fused r update + err ----
__global__ __launch_bounds__(256)
void kc_rowmv(const unsigned char* __restrict__ Kmat, const float* __restrict__ c_cur,
              float* __restrict__ r_cur, float* __restrict__ err,
              const int* __restrict__ run, int it)
{
    const int e = blockIdx.y;
    if (!run[it*E_ + e]) return;
    const int w = threadIdx.x >> 6, l = threadIdx.x & 63;
    const int row = blockIdx.x * 4 + w;
    const unsigned char* rp = Kmat + ((size_t)e*M_ + row) * M_;
    const float* cp = c_cur + e*M_;
    float p = 0.f;
#pragma unroll
    for (int i = 0; i < 4; ++i) {
        const int col = (i*64 + l) * 16;
        int4 raw = *(const int4*)(rp + col);
        float k[16]; kdec16(raw, k);
        float4 c0 = *(const float4*)(cp + col);
        float4 c1 = *(const float4*)(cp + col + 4);
        float4 c2 = *(const float4*)(cp + col + 8);
        float4 c3 = *(const float4*)(cp + col + 12);
        p += k[0]*c0.x + k[1]*c0.y + k[2]*c0.z + k[3]*c0.w
           + k[4]*c1.x + k[5]*c1.y + k[6]*c1.z + k[7]*c1.w
           + k[8]*c2.x + k[9]*c2.y + k[10]*c2.z + k[11]*c2.w
           + k[12]*c3.x + k[13]*c3.y + k[14]*c3.z + k[15]*c3.w;
    }
#pragma unroll
    for (int off = 32; off; off >>= 1) p += __shfl_down(p, off);
    __shared__ float bl[4];
    if (l == 0) {
        const float newr = 2.44140625e-4f / p;
        const float oldr = r_cur[e*M_ + row];
        r_cur[e*M_ + row] = newr;
        bl[w] = fabsf(newr - oldr);
    }
    __syncthreads();
    if (threadIdx.x == 0) atomicAdd(&err[it*E_ + e], bl[0]+bl[1]+bl[2]+bl[3]);
}

// ---- final loss: loss_e = sum r[m] c[n] K[m,n] sim, sim = 1 + 0.1*ln(K) ----
__global__ __launch_bounds__(256)
void loss_kernel(const unsigned char* __restrict__ Kmat, const float* __restrict__ r_cur,
                 const float* __restrict__ c_cur, float* __restrict__ loss_acc)
{
    const int e = blockIdx.y, ch = blockIdx.x, tid = threadIdx.x;
    __shared__ float rsh[RCHUNK];
    if (tid < RCHUNK) rsh[tid] = r_cur[e*M_ + ch*RCHUNK + tid];
    __syncthreads();
    float c16[16];
#pragma unroll
    for (int q = 0; q < 4; ++q) {
        float4 cv = *(const float4*)(c_cur + e*M_ + tid*16 + 4*q);
        c16[4*q] = cv.x; c16[4*q+1] = cv.y; c16[4*q+2] = cv.z; c16[4*q+3] = cv.w;
    }
    const unsigned char* base = Kmat + ((size_t)e*M_ + (size_t)ch*RCHUNK) * M_ + tid*16;
    float p = 0.f;
#pragma unroll 2
    for (int m = 0; m < RCHUNK; ++m) {
        const float rm = rsh[m];
        int4 raw = *(const int4*)(base + (size_t)m * M_);
        float k[16]; kdec16(raw, k);
        float q = 0.f;
#pragma unroll
        for (int j = 0; j < 16; ++j) {
            const float sim = fmaf(0.0693147180f, __log2f(k[j]), 1.0f);  // 1 + 0.1*ln K
            q = fmaf(c16[j] * k[j], sim, q);
        }
        p = fmaf(rm, q, p);
    }
#pragma unroll
    for (int off = 32; off; off >>= 1) p += __shfl_down(p, off);
    __shared__ float bl[4];
    if ((tid & 63) == 0) bl[tid >> 6] = p;
    __syncthreads();
    if (tid == 0) atomicAdd(&loss_acc[e], bl[0]+bl[1]+bl[2]+bl[3]);
}

__global__ void finalize(const float* __restrict__ loss_acc, const float* __restrict__ prev,
                         float* __restrict__ out)
{
    if (threadIdx.x == 0 && blockIdx.x == 0) {
        float l[E_], wgt[E_], sw = 0.f, tot = 0.f;
        for (int e = 0; e < E_; ++e) {
            l[e] = loss_acc[e];
            wgt[e] = expf(l[e] / (prev[e] + 1e-8f));
            sw += wgt[e];
        }
        for (int e = 0; e < E_; ++e) tot += (wgt[e] / sw * (float)E_) * l[e];
        out[0] = tot;
    }
}

extern "C" void kernel_launch(void* const* d_in, const int* in_sizes, int n_in,
                              void* d_out, int out_size, void* d_ws, size_t ws_size,
                              hipStream_t stream)
{
    (void)in_sizes; (void)n_in; (void)out_size; (void)ws_size;
    const float* gts   = (const float*)d_in[0];
    const float* feats = (const float*)d_in[1];
    const float* prev  = (const float*)d_in[2];
    float* out = (float*)d_out;
    char* ws = (char*)d_ws;

    unsigned char*  Kmat = (unsigned char*)ws;                       //  67,108,864 B
    __hip_bfloat16* Sb   = (__hip_bfloat16*)(ws + 67108864);         //  33,554,432 B
    __hip_bfloat16* Tb   = (__hip_bfloat16*)(ws + 100663296);        //  33,554,432 B
    float* part     = (float*)(ws + 134217728);                      //  16,777,216 B
    float* Kc0      = (float*)(ws + 150994944);                      //      65,536 B
    float* r_cur    = (float*)(ws + 151060480);                      //      65,536 B
    float* c_cur    = (float*)(ws + 151126016);                      //      65,536 B
    float* err      = (float*)(ws + 151191552);                      //          64 B
    int*   run      = (int*)  (ws + 151191616);                      //          64 B
    float* loss_acc = (float*)(ws + 151191680);                      //          16 B

    hipMemsetAsync(err, 0, 192, stream);                  // err + run + loss_acc
    hipMemsetAsync(Kc0, 0, E_*M_*sizeof(float), stream);
    normalize_bf16<<<dim3(E_*M_/4, 2), 256, 0, stream>>>(gts, feats, Sb, Tb);
    gemm_bt<<<dim3(32, 32, E_), 256, 0, stream>>>(Sb, Tb, Kmat, Kc0);

    // it = 0: row matvec fused into GEMM epilogue; r1+err0 computed inside kt
    kt_colmv<<<dim3(NCHUNK, E_), 256, 0, stream>>>(Kmat, Kc0, r_cur, part, err, run, 0, 1);
    c_update<<<dim3(M_/256, E_), 256, 0, stream>>>(part, c_cur, err, run, 0);

    for (int it = 1; it < NIT; ++it) {
        kc_rowmv<<<dim3(M_/4, E_), 256, 0, stream>>>(Kmat, c_cur, r_cur, err, run, it);
        kt_colmv<<<dim3(NCHUNK, E_), 256, 0, stream>>>(Kmat, Kc0, r_cur, part, err, run, it, 0);
        c_update<<<dim3(M_/256, E_), 256, 0, stream>>>(part, c_cur, err, run, it);
    }
    loss_kernel<<<dim3(NCHUNK, E_), 256, 0, stream>>>(Kmat, r_cur, c_cur, loss_acc);
    finalize<<<1, 64, 0, stream>>>(loss_acc, prev, out);
}

// Round 6
// 482.677 us; speedup vs baseline: 1.0568x; 1.0000x over previous
//
#include <hip/hip_runtime.h>
#include <hip/hip_bf16.h>

#define E_ 4
#define M_ 4096
#define D_ 1024
#define NIT 3
#define THRESH_ 0.01f
#define RCHUNK 16
#define NCHUNK (M_/RCHUNK)   // 256

typedef __attribute__((ext_vector_type(8))) short bf16x8;
typedef __attribute__((ext_vector_type(4))) float f32x4;

__device__ inline unsigned short f2bf(float x) {
    unsigned u = __float_as_uint(x);
    unsigned r = (u + 0x7FFFu + ((u >> 16) & 1u)) >> 16;  // RNE
    return (unsigned short)r;
}

// ---- custom fp8 for K: e4m3-style bits of (K*2^13); decode returns UNSCALED K ----
// K*8192 = exp2(14.4269504*s - 1.4269504); byte = clamp((bits>>20)-960); K = as_float((byte+856)<<20)
__device__ inline unsigned char kenc_sim(float s) {
    const float t = __builtin_amdgcn_exp2f(fmaf(14.4269504f, s, -1.4269504f));   // K * 8192
    unsigned u = __float_as_uint(t);
    u += 0x7FFFFu + ((u >> 20) & 1u);            // RNE to 3 mantissa bits
    int b = (int)(u >> 20) - 960;
    b = b < 0 ? 0 : (b > 255 ? 255 : b);
    return (unsigned char)b;
}

__device__ inline void kdec16(const int4& raw, float* k) {
    const unsigned* w = reinterpret_cast<const unsigned*>(&raw);
#pragma unroll
    for (int q = 0; q < 4; ++q) {
        const unsigned x = w[q];
        k[4*q+0] = __uint_as_float(((x & 0xFFu)         + 856u) << 20);
        k[4*q+1] = __uint_as_float((((x >> 8) & 0xFFu)  + 856u) << 20);
        k[4*q+2] = __uint_as_float((((x >> 16) & 0xFFu) + 856u) << 20);
        k[4*q+3] = __uint_as_float(( (x >> 24)          + 856u) << 20);
    }
}

// ---------------- normalize rows + convert to bf16; block(0,0) inits scalars ----------------
__global__ __launch_bounds__(256)
void normalize_bf16(const float* __restrict__ g, const float* __restrict__ f,
                    __hip_bfloat16* __restrict__ Sb, __hip_bfloat16* __restrict__ Tb,
                    float* __restrict__ err, float* __restrict__ loss_acc,
                    int* __restrict__ run)
{
    if (blockIdx.x == 0 && blockIdx.y == 0) {
        const int t = threadIdx.x;
        if (t < NIT*E_) err[t] = 0.f;
        if (t < E_) loss_acc[t] = 0.f;
        if (t < 4*E_) run[t] = 0;
    }
    const int w = threadIdx.x >> 6, l = threadIdx.x & 63;
    const size_t row = (size_t)blockIdx.x * 4 + w;       // 0..E*M-1
    const float* src = (blockIdx.y == 0 ? g : f) + row * (size_t)D_;
    __hip_bfloat16* dst = (blockIdx.y == 0 ? Sb : Tb) + row * (size_t)D_;
    float4 v[4];
    float ss = 0.f;
#pragma unroll
    for (int i = 0; i < 4; ++i) {
        v[i] = *(const float4*)(src + (i*64 + l) * 4);
        ss += v[i].x*v[i].x + v[i].y*v[i].y + v[i].z*v[i].z + v[i].w*v[i].w;
    }
#pragma unroll
    for (int off = 32; off; off >>= 1) ss += __shfl_xor(ss, off);
    const float inv = 1.f / fmaxf(sqrtf(ss), 1e-12f);
#pragma unroll
    for (int i = 0; i < 4; ++i) {
        ushort4 o;
        o.x = f2bf(v[i].x * inv); o.y = f2bf(v[i].y * inv);
        o.z = f2bf(v[i].z * inv); o.w = f2bf(v[i].w * inv);
        *(ushort4*)((unsigned short*)dst + (i*64 + l) * 4) = o;
    }
}

// ---- bf16 NT-GEMM: Kmat(fp8) = exp(10*(S@T^T - 1)); plain store epilogue ----
__global__ __launch_bounds__(256)
void gemm_bt(const __hip_bfloat16* __restrict__ Sb, const __hip_bfloat16* __restrict__ Tb,
             unsigned char* __restrict__ Kmat)
{
    const int e = blockIdx.z;
    const int brow = blockIdx.y, bcol = blockIdx.x;
    const int t = threadIdx.x, w = t >> 6, l = t & 63;
    const int wr = w >> 1, wc = w & 1;

    __shared__ __hip_bfloat16 Asl[128*32];
    __shared__ __hip_bfloat16 Bsl[128*32];

    const __hip_bfloat16* Ag = Sb + ((size_t)e*M_ + (size_t)brow*128) * D_;
    const __hip_bfloat16* Bg = Tb + ((size_t)e*M_ + (size_t)bcol*128) * D_;

    f32x4 acc[4][4] = {};

    for (int k0 = 0; k0 < D_; k0 += 32) {
#pragma unroll
        for (int i = 0; i < 2; ++i) {
            const int ci = i*256 + t;                 // 16B chunk id 0..511
            const int row = ci >> 2, c16 = ci & 3;
            const size_t goff = (size_t)row * D_ + k0 + c16*8;
            __builtin_amdgcn_global_load_lds(
                (const __attribute__((address_space(1))) void*)(Ag + goff),
                (__attribute__((address_space(3))) void*)(Asl + ci*8), 16, 0, 0);
            __builtin_amdgcn_global_load_lds(
                (const __attribute__((address_space(1))) void*)(Bg + goff),
                (__attribute__((address_space(3))) void*)(Bsl + ci*8), 16, 0, 0);
        }
        __syncthreads();
        bf16x8 af[4], bfr[4];
#pragma unroll
        for (int m = 0; m < 4; ++m)
            af[m] = *(const bf16x8*)(Asl + (wr*64 + m*16 + (l & 15)) * 32 + (l >> 4) * 8);
#pragma unroll
        for (int n = 0; n < 4; ++n)
            bfr[n] = *(const bf16x8*)(Bsl + (wc*64 + n*16 + (l & 15)) * 32 + (l >> 4) * 8);
#pragma unroll
        for (int m = 0; m < 4; ++m)
#pragma unroll
            for (int n = 0; n < 4; ++n)
                acc[m][n] = __builtin_amdgcn_mfma_f32_16x16x32_bf16(af[m], bfr[n], acc[m][n], 0, 0, 0);
        __syncthreads();
    }

    // C/D layout: col = lane&15, row = (lane>>4)*4 + reg
    unsigned char* Cg = Kmat + (size_t)e*M_*M_;
    const size_t crow0 = (size_t)brow*128 + wr*64;
    const int ccol0 = bcol*128 + wc*64;
#pragma unroll
    for (int m = 0; m < 4; ++m)
#pragma unroll
        for (int j = 0; j < 4; ++j) {
            const size_t r = crow0 + m*16 + (l >> 4)*4 + j;
#pragma unroll
            for (int n = 0; n < 4; ++n)
                Cg[r * M_ + ccol0 + n*16 + (l & 15)] = kenc_sim(acc[m][n][j]);
        }
}

// ---- one Sinkhorn half-iteration pair, fused per 16-row chunk:
//      sweep1: Kc[m] = K[m,:]·c  (c==1 for it 0)  -> r[m] = u/Kc[m], err
//      sweep2: part[ch][n] = sum_m r[m]*K[m,n]   (re-reads chunk, L2/LLC-hot) ----
__global__ __launch_bounds__(256)
void sink_iter(const unsigned char* __restrict__ Kmat, const float* __restrict__ c_cur,
               float* __restrict__ r_cur, float* __restrict__ part,
               float* __restrict__ err, const int* __restrict__ run, int it)
{
    const int e = blockIdx.y, ch = blockIdx.x, tid = threadIdx.x;
    if (it > 0 && !run[it*E_ + e]) return;

    float c16[16];
    if (it == 0) {
#pragma unroll
        for (int j = 0; j < 16; ++j) c16[j] = 1.f;
    } else {
        const float* cp = c_cur + e*M_ + tid*16;
#pragma unroll
        for (int q = 0; q < 4; ++q) {
            float4 cv = *(const float4*)(cp + 4*q);
            c16[4*q]=cv.x; c16[4*q+1]=cv.y; c16[4*q+2]=cv.z; c16[4*q+3]=cv.w;
        }
    }

    __shared__ float red[RCHUNK][256];   // 16 KB
    __shared__ float rsh[RCHUNK];

    const unsigned char* base = Kmat + ((size_t)e*M_ + (size_t)ch*RCHUNK) * M_ + tid*16;

    // sweep 1: per-thread row-dot partials
#pragma unroll 4
    for (int m = 0; m < RCHUNK; ++m) {
        int4 raw = *(const int4*)(base + (size_t)m * M_);
        float k[16]; kdec16(raw, k);
        float p = 0.f;
#pragma unroll
        for (int j = 0; j < 16; ++j) p = fmaf(k[j], c16[j], p);
        red[m][tid] = p;
    }
    __syncthreads();

    // reduce: wave w owns rows 4w..4w+3
    const int w = tid >> 6, l = tid & 63;
    float werr = 0.f;
#pragma unroll
    for (int k0 = 0; k0 < 4; ++k0) {
        const int m = w*4 + k0;
        float s = red[m][l] + red[m][l+64] + red[m][l+128] + red[m][l+192];
#pragma unroll
        for (int off = 32; off; off >>= 1) s += __shfl_xor(s, off);
        if (l == 0) {
            const float newr = 2.44140625e-4f / s;          // u/Kc, u = 1/4096
            const int row = e*M_ + ch*RCHUNK + m;
            const float oldr = (it == 0) ? 1.f : r_cur[row];
            r_cur[row] = newr;
            rsh[m] = newr;
            werr += fabsf(newr - oldr);
        }
    }
    if (l == 0) atomicAdd(&err[it*E_ + e], werr);
    __syncthreads();

    // sweep 2: colsum partials with fresh r (chunk is cache-hot)
    float acc[16];
#pragma unroll
    for (int j = 0; j < 16; ++j) acc[j] = 0.f;
#pragma unroll 4
    for (int m = 0; m < RCHUNK; ++m) {
        const float rm = rsh[m];
        int4 raw = *(const int4*)(base + (size_t)m * M_);
        float k[16]; kdec16(raw, k);
#pragma unroll
        for (int j = 0; j < 16; ++j) acc[j] = fmaf(rm, k[j], acc[j]);
    }
    float* pp = part + ((size_t)e*NCHUNK + ch) * M_ + tid*16;
#pragma unroll
    for (int q = 0; q < 4; ++q) {
        float4 o = {acc[4*q], acc[4*q+1], acc[4*q+2], acc[4*q+3]};
        *(float4*)(pp + 4*q) = o;
    }
}

// ---- c = v/colsum; fused convergence-flag update ----
__global__ __launch_bounds__(256)
void c_update(const float* __restrict__ part, float* __restrict__ c_cur,
              const float* __restrict__ err, int* __restrict__ run, int it)
{
    const int e = blockIdx.y;
    const int active = (it == 0) ? 1 : run[it*E_ + e];
    if (blockIdx.x == 0 && threadIdx.x == 0)
        run[(it+1)*E_ + e] = active && (err[it*E_ + e] * (1.0f / M_) >= THRESH_);
    if (!active) return;
    const int l = threadIdx.x & 63, q = threadIdx.x >> 6;
    const int n = blockIdx.x * 64 + l;
    float s = 0.f;
#pragma unroll 8
    for (int ch = q; ch < NCHUNK; ch += 4)
        s += part[((size_t)e*NCHUNK + ch) * M_ + n];
    __shared__ float red[4][64];
    red[q][l] = s;
    __syncthreads();
    if (q == 0) {
        s = red[0][l] + red[1][l] + red[2][l] + red[3][l];
        c_cur[e*M_ + n] = 2.44140625e-4f / s;               // v/colsum, v = 1/4096
    }
}

// ---- final loss: loss_e = sum r[m] c[n] K[m,n] sim, sim = 1 + 0.1*ln(K) ----
__global__ __launch_bounds__(256)
void loss_kernel(const unsigned char* __restrict__ Kmat, const float* __restrict__ r_cur,
                 const float* __restrict__ c_cur, float* __restrict__ loss_acc)
{
    const int e = blockIdx.y, ch = blockIdx.x, tid = threadIdx.x;
    __shared__ float rsh[RCHUNK];
    if (tid < RCHUNK) rsh[tid] = r_cur[e*M_ + ch*RCHUNK + tid];
    __syncthreads();
    float c16[16];
#pragma unroll
    for (int q = 0; q < 4; ++q) {
        float4 cv = *(const float4*)(c_cur + e*M_ + tid*16 + 4*q);
        c16[4*q] = cv.x; c16[4*q+1] = cv.y; c16[4*q+2] = cv.z; c16[4*q+3] = cv.w;
    }
    const unsigned char* base = Kmat + ((size_t)e*M_ + (size_t)ch*RCHUNK) * M_ + tid*16;
    float p = 0.f;
#pragma unroll 2
    for (int m = 0; m < RCHUNK; ++m) {
        const float rm = rsh[m];
        int4 raw = *(const int4*)(base + (size_t)m * M_);
        float k[16]; kdec16(raw, k);
        float q = 0.f;
#pragma unroll
        for (int j = 0; j < 16; ++j) {
            const float sim = fmaf(0.0693147180f, __log2f(k[j]), 1.0f);  // 1 + 0.1*ln K
            q = fmaf(c16[j] * k[j], sim, q);
        }
        p = fmaf(rm, q, p);
    }
#pragma unroll
    for (int off = 32; off; off >>= 1) p += __shfl_down(p, off);
    __shared__ float bl[4];
    if ((tid & 63) == 0) bl[tid >> 6] = p;
    __syncthreads();
    if (tid == 0) atomicAdd(&loss_acc[e], bl[0]+bl[1]+bl[2]+bl[3]);
}

__global__ void finalize(const float* __restrict__ loss_acc, const float* __restrict__ prev,
                         float* __restrict__ out)
{
    if (threadIdx.x == 0 && blockIdx.x == 0) {
        float l[E_], wgt[E_], sw = 0.f, tot = 0.f;
        for (int e = 0; e < E_; ++e) {
            l[e] = loss_acc[e];
            wgt[e] = expf(l[e] / (prev[e] + 1e-8f));
            sw += wgt[e];
        }
        for (int e = 0; e < E_; ++e) tot += (wgt[e] / sw * (float)E_) * l[e];
        out[0] = tot;
    }
}

extern "C" void kernel_launch(void* const* d_in, const int* in_sizes, int n_in,
                              void* d_out, int out_size, void* d_ws, size_t ws_size,
                              hipStream_t stream)
{
    (void)in_sizes; (void)n_in; (void)out_size; (void)ws_size;
    const float* gts   = (const float*)d_in[0];
    const float* feats = (const float*)d_in[1];
    const float* prev  = (const float*)d_in[2];
    float* out = (float*)d_out;
    char* ws = (char*)d_ws;

    unsigned char*  Kmat = (unsigned char*)ws;                       //  67,108,864 B
    __hip_bfloat16* Sb   = (__hip_bfloat16*)(ws + 67108864);         //  33,554,432 B
    __hip_bfloat16* Tb   = (__hip_bfloat16*)(ws + 100663296);        //  33,554,432 B
    float* part     = (float*)(ws + 134217728);                      //  16,777,216 B
    float* r_cur    = (float*)(ws + 150994944);                      //      65,536 B
    float* c_cur    = (float*)(ws + 151060480);                      //      65,536 B
    float* err      = (float*)(ws + 151126016);                      //          48 B
    float* loss_acc = (float*)(ws + 151126080);                      //          16 B
    int*   run      = (int*)  (ws + 151126144);                      //          64 B

    normalize_bf16<<<dim3(E_*M_/4, 2), 256, 0, stream>>>(gts, feats, Sb, Tb,
                                                         err, loss_acc, run);
    gemm_bt<<<dim3(32, 32, E_), 256, 0, stream>>>(Sb, Tb, Kmat);

    for (int it = 0; it < NIT; ++it) {
        sink_iter<<<dim3(NCHUNK, E_), 256, 0, stream>>>(Kmat, c_cur, r_cur, part, err, run, it);
        c_update<<<dim3(M_/64, E_), 256, 0, stream>>>(part, c_cur, err, run, it);
    }
    loss_kernel<<<dim3(NCHUNK, E_), 256, 0, stream>>>(Kmat, r_cur, c_cur, loss_acc);
    finalize<<<1, 64, 0, stream>>>(loss_acc, prev, out);
}